// Round 12
// baseline (334.664 us; speedup 1.0000x reference)
//
#include <hip/hip_runtime.h>
#include <hip/hip_bf16.h>
#include <cstdint>

// ---------------------------------------------------------------------------
// GAT 2-layer model on MI355X.
// R11: online-softmax fused into spmm (339->312us). spmm VALU 51%: ~45% of
//   chunk work is tail padding (deg~17 -> 2nd chunk mostly invalid slots).
// R12: (a) spmm tail-trim: full 16-chunks keep the 16-deep burst; the last
//   partial chunk runs 4-row packs behind group-uniform guards (wave execz
//   skips when co-resident nodes have similar remainders).
//   (b) layer-2 pooling fused into spmm epilogue (blocks = 16 consecutive
//   nodes, same as post_pool): accbuf + post_pool kernel deleted.
//   (c) binned edges packed to 4B: (dst&255)<<24 | src  (src < 2^17).
// ---------------------------------------------------------------------------

#define BIN_SHIFT 8
#define BIN_NODES 256
#define PLACE_CHUNK 8192

__device__ __forceinline__ float wave_reduce_sum(float v) {
#pragma unroll
  for (int off = 32; off > 0; off >>= 1) v += __shfl_xor(v, off, 64);
  return v;
}

__device__ __forceinline__ unsigned short f2bf(float f) {  // RNE
  unsigned int u = __float_as_uint(f);
  u += 0x7fffu + ((u >> 16) & 1u);
  return (unsigned short)(u >> 16);
}
__device__ __forceinline__ float bf2f(unsigned short u) {
  return __uint_as_float(((unsigned int)u) << 16);
}

// ---------------- CSR build (binned, low write-amplification) ----------------

__global__ void bin_count_kernel(const int* __restrict__ ei, int E, int M, int NB,
                                 int* __restrict__ binCnt) {
  extern __shared__ int hist[];
  for (int i = threadIdx.x; i < NB; i += blockDim.x) hist[i] = 0;
  __syncthreads();
  int stride = gridDim.x * blockDim.x;
  for (int t = blockIdx.x * blockDim.x + threadIdx.x; t < M; t += stride) {
    int d = (t < E) ? ei[E + t] : (t - E);
    atomicAdd(&hist[d >> BIN_SHIFT], 1);
  }
  __syncthreads();
  for (int i = threadIdx.x; i < NB; i += blockDim.x)
    if (hist[i]) atomicAdd(&binCnt[i], hist[i]);
}

// block 0: exclusive scan of binCnt -> binBase/binCursor (64 lanes).
// blocks 1..2: gstart[g] = lower_bound(batch, g) (batch sorted).
__global__ void scan_bounds_kernel(const int* __restrict__ binCnt, int NB,
                                   int* __restrict__ binBase, int* __restrict__ binCursor,
                                   const int* __restrict__ batch, int* __restrict__ gstart,
                                   int N, int G) {
  if (blockIdx.x == 0) {
    int lane = threadIdx.x;
    if (lane >= 64) return;
    int per = (NB + 63) / 64;  // <= 8
    int vals[8];
    int base = lane * per;
    int s = 0;
#pragma unroll
    for (int i = 0; i < 8; i++) {
      int idx = base + i;
      int v = (i < per && idx < NB) ? binCnt[idx] : 0;
      vals[i] = v;
      s += v;
    }
    int x = s;
#pragma unroll
    for (int off = 1; off < 64; off <<= 1) {
      int u = __shfl_up(x, off, 64);
      if (lane >= off) x += u;
    }
    int excl = x - s;
#pragma unroll
    for (int i = 0; i < 8; i++) {
      int idx = base + i;
      if (i < per && idx < NB) {
        binBase[idx] = excl;
        binCursor[idx] = excl;
      }
      excl += vals[i];
    }
    if (lane == 63) binBase[NB] = x;  // == M
  } else {
    int g = (blockIdx.x - 1) * 256 + threadIdx.x;
    if (g > G) return;
    int lo = 0, hi = N;
    while (lo < hi) {
      int mid = (lo + hi) >> 1;
      if (batch[mid] < g) lo = mid + 1;
      else hi = mid;
    }
    gstart[g] = lo;
  }
}

__global__ __launch_bounds__(256) void bin_place_kernel(
    const int* __restrict__ ei, int E, int M, int NB,
    int* __restrict__ binCursor, unsigned int* __restrict__ binned) {
  extern __shared__ int sh[];
  int* res = sh;       // [NB]
  int* cur = sh + NB;  // [NB]
  const int t = threadIdx.x;
  const int cbase = blockIdx.x * PLACE_CHUNK;
  const int cend = min(cbase + PLACE_CHUNK, M);

  for (int i = t; i < NB; i += 256) cur[i] = 0;
  __syncthreads();
  for (int i = cbase + t; i < cend; i += 256) {
    int d = (i < E) ? ei[E + i] : (i - E);
    atomicAdd(&cur[d >> BIN_SHIFT], 1);
  }
  __syncthreads();
  for (int i = t; i < NB; i += 256) {
    int c = cur[i];
    res[i] = c ? atomicAdd(&binCursor[i], c) : 0;
  }
  __syncthreads();
  for (int i = t; i < NB; i += 256) cur[i] = 0;
  __syncthreads();
  for (int i = cbase + t; i < cend; i += 256) {
    int s, d;
    if (i < E) { s = ei[i]; d = ei[E + i]; } else { s = d = i - E; }
    int b = d >> BIN_SHIFT;
    int r = atomicAdd(&cur[b], 1);
    binned[res[b] + r] = ((unsigned int)(d & (BIN_NODES - 1)) << 24) | (unsigned int)s;
  }
}

__global__ __launch_bounds__(256) void csr_finalize_kernel(
    const unsigned int* __restrict__ binned, const int* __restrict__ binBase,
    int* __restrict__ rowptr, int* __restrict__ csrc, int N, int NB, int M) {
  __shared__ int cnt[256];
  __shared__ int off[256];
  __shared__ int wsum[4];
  const int b = blockIdx.x;
  const int t = threadIdx.x;
  const int nodeBase = b << BIN_SHIFT;
  const int eStart = binBase[b], eEnd = binBase[b + 1];

  cnt[t] = 0;
  __syncthreads();
  for (int i = eStart + t; i < eEnd; i += 256) {
    atomicAdd(&cnt[binned[i] >> 24], 1);
  }
  __syncthreads();
  {
    int lane = t & 63, wv = t >> 6;
    int v = cnt[t];
    int x = v;
#pragma unroll
    for (int o = 1; o < 64; o <<= 1) {
      int u = __shfl_up(x, o, 64);
      if (lane >= o) x += u;
    }
    if (lane == 63) wsum[wv] = x;
    __syncthreads();
    int woff = 0;
    for (int j = 0; j < wv; j++) woff += wsum[j];
    off[t] = woff + x - v;
  }
  __syncthreads();
  int node = nodeBase + t;
  if (node < N) rowptr[node] = eStart + off[t];
  if (b == NB - 1 && t == 0) rowptr[N] = M;
  cnt[t] = off[t];
  __syncthreads();
  for (int i = eStart + t; i < eEnd; i += 256) {
    unsigned int pk = binned[i];
    int r = atomicAdd(&cnt[pk >> 24], 1);
    csrc[eStart + r] = (int)(pk & 0xFFFFFFu);
  }
}

// ---------------- dense compute ----------------

// hb[N][64] (bf16) = A[N][KDIM] @ W[KDIM][64]; fused al epilogue from the
// exact fp32 accumulators.
template <int KDIM>
__global__ __launch_bounds__(256) void gemm64(const float* __restrict__ A,
                                              const float* __restrict__ W,
                                              unsigned short* __restrict__ hb,
                                              const float* __restrict__ a_src,
                                              const float* __restrict__ a_dst,
                                              float* __restrict__ alsrc,
                                              float* __restrict__ aldst, int N) {
  __shared__ float As[32][68];
  __shared__ float Ws[32][68];
  const int block_m = blockIdx.x * 64;
  const int t = threadIdx.x;
  const int tc = t & 15;
  const int tr = t >> 4;
  const int c0 = tc * 4, r0 = tr * 4;
  float acc[4][4] = {};

  for (int kc = 0; kc < KDIM; kc += 32) {
    for (int q = t; q < 512; q += 256) {
      int node = q >> 3, f4 = q & 7;
      int gn = block_m + node;
      if (gn >= N) gn = N - 1;
      const float4 v = *(const float4*)(A + (size_t)gn * KDIM + kc + f4 * 4);
      As[f4 * 4 + 0][node] = v.x;
      As[f4 * 4 + 1][node] = v.y;
      As[f4 * 4 + 2][node] = v.z;
      As[f4 * 4 + 3][node] = v.w;
    }
    for (int q = t; q < 512; q += 256) {
      int k = q >> 4, f4 = q & 15;
      const float4 v = *(const float4*)(W + (size_t)(kc + k) * 64 + f4 * 4);
      *(float4*)&Ws[k][f4 * 4] = v;
    }
    __syncthreads();
#pragma unroll
    for (int k = 0; k < 32; ++k) {
      float4 a = *(const float4*)&As[k][r0];
      float4 b = *(const float4*)&Ws[k][c0];
      acc[0][0] += a.x * b.x; acc[0][1] += a.x * b.y; acc[0][2] += a.x * b.z; acc[0][3] += a.x * b.w;
      acc[1][0] += a.y * b.x; acc[1][1] += a.y * b.y; acc[1][2] += a.y * b.z; acc[1][3] += a.y * b.w;
      acc[2][0] += a.z * b.x; acc[2][1] += a.z * b.y; acc[2][2] += a.z * b.z; acc[2][3] += a.z * b.w;
      acc[3][0] += a.w * b.x; acc[3][1] += a.w * b.y; acc[3][2] += a.w * b.z; acc[3][3] += a.w * b.w;
    }
    __syncthreads();
  }

  const float as0 = a_src[c0], as1 = a_src[c0 + 1], as2 = a_src[c0 + 2], as3 = a_src[c0 + 3];
  const float ad0 = a_dst[c0], ad1 = a_dst[c0 + 1], ad2 = a_dst[c0 + 2], ad3 = a_dst[c0 + 3];
#pragma unroll
  for (int i = 0; i < 4; ++i) {
    int gn = block_m + r0 + i;
    if (gn < N) {
      ushort4 u;
      u.x = f2bf(acc[i][0]); u.y = f2bf(acc[i][1]);
      u.z = f2bf(acc[i][2]); u.w = f2bf(acc[i][3]);
      *(ushort4*)(hb + (size_t)gn * 64 + c0) = u;
    }
    float ps = acc[i][0] * as0 + acc[i][1] * as1 + acc[i][2] * as2 + acc[i][3] * as3;
    float pd = acc[i][0] * ad0 + acc[i][1] * ad1 + acc[i][2] * ad2 + acc[i][3] * ad3;
#pragma unroll
    for (int off = 1; off < 16; off <<= 1) {
      ps += __shfl_xor(ps, off, 64);
      pd += __shfl_xor(pd, off, 64);
    }
    if (tc == 0 && gn < N) {
      alsrc[gn] = ps;
      aldst[gn] = pd;
    }
  }
}

// Fused softmax + spmm + epilogue. One 16-lane group per dst node.
// Full 16-edge chunks: unconditional 16-deep row burst (no masking).
// Tail chunk: 4-row packs behind group-uniform guards (wave execz skips).
// POOL=0: dense bias+ELU row write (layer 1).
// POOL=1: bias+ELU then block-level pool reduction (16 consecutive nodes,
//         LDS reduce, one atomic per feature per graph-uniform block).
template <int POOL>
__global__ __launch_bounds__(256) void spmm_fused_kernel(
    const int* __restrict__ rowptr, const int* __restrict__ csrc,
    const float* __restrict__ alsrc, const float* __restrict__ aldst,
    const unsigned short* __restrict__ hb, const float* __restrict__ bias,
    float* __restrict__ outbuf, const int* __restrict__ batch,
    float* __restrict__ pool, int N) {
  const int t = threadIdx.x;
  const int l = t & 15;   // slot within group
  const int gb = t & 48;  // group base lane within wave
  const int node = blockIdx.x * 16 + (t >> 4);
  const bool active = node < N;

  float4 r = make_float4(0.f, 0.f, 0.f, 0.f);
  if (active) {
    const int start = rowptr[node];
    const int end = rowptr[node + 1];
    const float ad = aldst[node];

    float m = -1e30f;
    float ssum = 0.f;
    float4 acc0 = make_float4(0.f, 0.f, 0.f, 0.f);
    float4 acc1 = make_float4(0.f, 0.f, 0.f, 0.f);
    float4 acc2 = make_float4(0.f, 0.f, 0.f, 0.f);
    float4 acc3 = make_float4(0.f, 0.f, 0.f, 0.f);

    int base = start;
    for (; base + 16 <= end; base += 16) {  // full chunks: no masking
      int s = csrc[base + l];
      float al = alsrc[s];

      ushort4 u[16];
#pragma unroll
      for (int j = 0; j < 16; ++j) {
        int sj = __shfl(s, gb + j, 64);
        u[j] = *(const ushort4*)(hb + (size_t)sj * 64 + l * 4);
      }

      float e = al + ad;
      e = (e > 0.f) ? e : 0.2f * e;
      float cmax = e;
#pragma unroll
      for (int off = 1; off < 16; off <<= 1) cmax = fmaxf(cmax, __shfl_xor(cmax, off, 64));
      float newm = fmaxf(m, cmax);
      float scale = __expf(m - newm);
      float w = __expf(e - newm);
      float wsum = w;
#pragma unroll
      for (int off = 1; off < 16; off <<= 1) wsum += __shfl_xor(wsum, off, 64);
      ssum = ssum * scale + wsum;
      acc0.x *= scale; acc0.y *= scale; acc0.z *= scale; acc0.w *= scale;
      acc1.x *= scale; acc1.y *= scale; acc1.z *= scale; acc1.w *= scale;
      acc2.x *= scale; acc2.y *= scale; acc2.z *= scale; acc2.w *= scale;
      acc3.x *= scale; acc3.y *= scale; acc3.z *= scale; acc3.w *= scale;
      m = newm;

#pragma unroll
      for (int j = 0; j < 16; ++j) {
        float wj = __shfl(w, gb + j, 64);
        float4* A = ((j & 3) == 0) ? &acc0 : ((j & 3) == 1) ? &acc1
                  : ((j & 3) == 2) ? &acc2 : &acc3;
        A->x += wj * bf2f(u[j].x);
        A->y += wj * bf2f(u[j].y);
        A->z += wj * bf2f(u[j].z);
        A->w += wj * bf2f(u[j].w);
      }
    }

    if (base < end) {  // tail chunk: 4-row packs, group-uniform guards
      int i = base + l;
      bool valid = i < end;
      int s = valid ? csrc[i] : 0;
      float al = alsrc[s];

      float e = al + ad;
      e = (e > 0.f) ? e : 0.2f * e;
      if (!valid) e = -1e30f;
      float cmax = e;
#pragma unroll
      for (int off = 1; off < 16; off <<= 1) cmax = fmaxf(cmax, __shfl_xor(cmax, off, 64));
      float newm = fmaxf(m, cmax);
      float scale = __expf(m - newm);
      float w = valid ? __expf(e - newm) : 0.f;
      float wsum = w;
#pragma unroll
      for (int off = 1; off < 16; off <<= 1) wsum += __shfl_xor(wsum, off, 64);
      ssum = ssum * scale + wsum;
      acc0.x *= scale; acc0.y *= scale; acc0.z *= scale; acc0.w *= scale;
      acc1.x *= scale; acc1.y *= scale; acc1.z *= scale; acc1.w *= scale;
      acc2.x *= scale; acc2.y *= scale; acc2.z *= scale; acc2.w *= scale;
      acc3.x *= scale; acc3.y *= scale; acc3.z *= scale; acc3.w *= scale;
      m = newm;

#pragma unroll
      for (int jb = 0; jb < 16; jb += 4) {
        if (base + jb < end) {  // group-uniform -> execz skip when all done
          ushort4 u[4];
          float wj[4];
#pragma unroll
          for (int j = 0; j < 4; ++j) {
            int sj = __shfl(s, gb + jb + j, 64);
            wj[j] = __shfl(w, gb + jb + j, 64);
            u[j] = *(const ushort4*)(hb + (size_t)sj * 64 + l * 4);
          }
#pragma unroll
          for (int j = 0; j < 4; ++j) {
            float4* A = (j == 0) ? &acc0 : (j == 1) ? &acc1 : (j == 2) ? &acc2 : &acc3;
            A->x += wj[j] * bf2f(u[j].x);
            A->y += wj[j] * bf2f(u[j].y);
            A->z += wj[j] * bf2f(u[j].z);
            A->w += wj[j] * bf2f(u[j].w);
          }
        }
      }
    }

    float inv = 1.0f / ssum;  // >= 1 edge (self-loop)
    r.x = ((acc0.x + acc1.x) + (acc2.x + acc3.x)) * inv;
    r.y = ((acc0.y + acc1.y) + (acc2.y + acc3.y)) * inv;
    r.z = ((acc0.z + acc1.z) + (acc2.z + acc3.z)) * inv;
    r.w = ((acc0.w + acc1.w) + (acc2.w + acc3.w)) * inv;
    const float4 b4 = *(const float4*)(bias + l * 4);
    r.x += b4.x; r.y += b4.y; r.z += b4.z; r.w += b4.w;
    r.x = (r.x > 0.f) ? r.x : expm1f(r.x);
    r.y = (r.y > 0.f) ? r.y : expm1f(r.y);
    r.z = (r.z > 0.f) ? r.z : expm1f(r.z);
    r.w = (r.w > 0.f) ? r.w : expm1f(r.w);
  }

  if (!POOL) {
    if (active) *(float4*)(outbuf + (size_t)node * 64 + l * 4) = r;
  } else {
    // block covers 16 consecutive nodes (batch sorted) — R7's proven scheme
    __shared__ float4 red4[16][17];
    __shared__ int sB[16];
    __shared__ int uni;
    const int blkBase = blockIdx.x * 16;
    if (t < 16) {
      int nn = blkBase + t;
      sB[t] = (nn < N) ? batch[nn] : -1;
    }
    __syncthreads();
    if (t == 0) {
      int u = (blkBase + 15 < N);
      for (int i = 1; i < 16; i++) u &= (sB[i] == sB[0]);
      uni = u;
    }
    if (!active) r = make_float4(0.f, 0.f, 0.f, 0.f);
    red4[t >> 4][l] = r;
    __syncthreads();
    if (t < 64) {
      const float* rf = (const float*)red4;  // row stride 68 floats
      if (uni) {
        float sum = 0.f;
#pragma unroll
        for (int n = 0; n < 16; n++) sum += rf[n * 68 + t];
        atomicAdd(&pool[(size_t)sB[0] * 64 + t], sum);
      } else {
        for (int n = 0; n < 16; n++) {
          int g = sB[n];
          if (g >= 0) atomicAdd(&pool[(size_t)g * 64 + t], rf[n * 68 + t]);
        }
      }
    }
  }
}

// out[g] = (pool[g,:]/cnt[g]) . Wfc + bfc ; cnt from sorted-batch bounds.
__global__ void final_kernel(const float* __restrict__ pool, const int* __restrict__ gstart,
                             const float* __restrict__ Wfc, const float* __restrict__ bfc,
                             float* __restrict__ out, int G) {
  int wid = (blockIdx.x * blockDim.x + threadIdx.x) >> 6;
  int lane = threadIdx.x & 63;
  if (wid >= G) return;
  float c = (float)max(gstart[wid + 1] - gstart[wid], 1);
  float v = pool[(size_t)wid * 64 + lane] * (1.0f / c) * Wfc[lane];
  v = wave_reduce_sum(v);
  if (lane == 0) out[wid] = v + bfc[0];
}

// ---------------------------------------------------------------------------

extern "C" void kernel_launch(void* const* d_in, const int* in_sizes, int n_in,
                              void* d_out, int out_size, void* d_ws, size_t ws_size,
                              hipStream_t stream) {
  const float* x     = (const float*)d_in[0];
  const int*   ei    = (const int*)d_in[1];
  const int*   batch = (const int*)d_in[2];
  const float* W1    = (const float*)d_in[3];
  const float* asrc1 = (const float*)d_in[4];
  const float* adst1 = (const float*)d_in[5];
  const float* b1    = (const float*)d_in[6];
  const float* W2    = (const float*)d_in[7];
  const float* asrc2 = (const float*)d_in[8];
  const float* adst2 = (const float*)d_in[9];
  const float* b2    = (const float*)d_in[10];
  const float* Wfc   = (const float*)d_in[11];
  const float* bfc   = (const float*)d_in[12];
  float* out = (float*)d_out;

  const int N = in_sizes[0] / 128;  // 100000
  const int E = in_sizes[1] / 2;    // 1600000
  const int G = 256;
  const int M = E + N;              // edges incl self-loops
  const int NB = (N + BIN_NODES - 1) >> BIN_SHIFT;  // 391 bins

  // workspace carve (256B aligned)
  char* p = (char*)d_ws;
  auto alloc = [&](size_t bytes) {
    char* r = p;
    p += (bytes + 255) & ~size_t(255);
    return r;
  };
  float*          h1e    = (float*)alloc((size_t)N * 64 * 4);
  unsigned short* hb     = (unsigned short*)alloc((size_t)N * 64 * 2);
  float* alsrc  = (float*)alloc((size_t)N * 4);
  float* aldst  = (float*)alloc((size_t)N * 4);
  int*   rowptr = (int*)alloc((size_t)(N + 1) * 4);
  int*   csrc   = (int*)alloc((size_t)M * 4);
  unsigned int* binned = (unsigned int*)alloc((size_t)M * 4);
  int*   binCnt = (int*)alloc((size_t)NB * 4);
  int*   binBase = (int*)alloc((size_t)(NB + 1) * 4);
  int*   binCursor = (int*)alloc((size_t)NB * 4);
  float* pool   = (float*)alloc((size_t)G * 64 * 4);
  int*   gstart = (int*)alloc((size_t)(G + 1) * 4);

  // ---- CSR build (binned) + graph bounds ----
  hipMemsetAsync(binCnt, 0, (size_t)NB * 4, stream);
  bin_count_kernel<<<512, 256, NB * 4, stream>>>(ei, E, M, NB, binCnt);
  scan_bounds_kernel<<<3, 256, 0, stream>>>(binCnt, NB, binBase, binCursor,
                                            batch, gstart, N, G);
  bin_place_kernel<<<(M + PLACE_CHUNK - 1) / PLACE_CHUNK, 256, 2 * NB * 4, stream>>>(
      ei, E, M, NB, binCursor, binned);
  csr_finalize_kernel<<<NB, 256, 0, stream>>>(binned, binBase, rowptr, csrc, N, NB, M);

  // ---- layer 1 ----
  gemm64<128><<<(N + 63) / 64, 256, 0, stream>>>(x, W1, hb, asrc1, adst1, alsrc, aldst, N);
  spmm_fused_kernel<0><<<(N + 15) / 16, 256, 0, stream>>>(rowptr, csrc, alsrc, aldst,
                                                          hb, b1, h1e, nullptr, nullptr, N);

  // ---- layer 2 (pool fused into spmm epilogue) ----
  gemm64<64><<<(N + 63) / 64, 256, 0, stream>>>(h1e, W2, hb, asrc2, adst2, alsrc, aldst, N);
  hipMemsetAsync(pool, 0, (size_t)G * 64 * 4, stream);
  spmm_fused_kernel<1><<<(N + 15) / 16, 256, 0, stream>>>(rowptr, csrc, alsrc, aldst,
                                                          hb, b2, nullptr, batch, pool, N);

  // ---- readout ----
  final_kernel<<<(G * 64 + 255) / 256, 256, 0, stream>>>(pool, gstart, Wfc, bfc, out, G);
}

// Round 13
// 293.262 us; speedup vs baseline: 1.1412x; 1.1412x over previous
//
#include <hip/hip_runtime.h>
#include <hip/hip_bf16.h>
#include <cstdint>

// ---------------------------------------------------------------------------
// GAT 2-layer model on MI355X.
// R12 post-mortem (REGRESSION 312->335): tail-trim guards were group-uniform
//   (wave divergence, broke load hoisting) and pool fusion cost occupancy
//   (LDS+sync in the hot kernel). Both reverted.
// R13: spmm restored to R11's proven form (43us). CSR build redesigned with
//   fixed per-bin capacity (CAP=6144 = mean 4348 + 27 sigma): bins need not
//   be contiguous because spmm only needs per-node [rowbeg,rowend). Deletes
//   bin_count + scan (one full ei pass + a kernel); bin_place reads ei ONCE
//   (rank via single LDS-atomic pass, rank+bin kept in registers).
// ---------------------------------------------------------------------------

#define BIN_SHIFT 8
#define BIN_NODES 256
#define BIN_CAP 6144
#define PLACE_CHUNK 2048

__device__ __forceinline__ float wave_reduce_sum(float v) {
#pragma unroll
  for (int off = 32; off > 0; off >>= 1) v += __shfl_xor(v, off, 64);
  return v;
}

__device__ __forceinline__ unsigned short f2bf(float f) {  // RNE
  unsigned int u = __float_as_uint(f);
  u += 0x7fffu + ((u >> 16) & 1u);
  return (unsigned short)(u >> 16);
}
__device__ __forceinline__ float bf2f(unsigned short u) {
  return __uint_as_float(((unsigned int)u) << 16);
}

// ---------------- CSR build (capacity-binned, single ei pass) ----------------

// Place edges into binned[b*BIN_CAP + ...]. One LDS-atomic pass for ranks
// (held in registers), one global reservation per (block,bin), then packed
// writes: (dst&255)<<24 | src.
__global__ __launch_bounds__(256) void bin_place_kernel(
    const int* __restrict__ ei, int E, int M, int NB,
    int* __restrict__ binCursor, unsigned int* __restrict__ binned) {
  __shared__ int cur[512];
  __shared__ int res[512];
  const int t = threadIdx.x;
  const int cbase = blockIdx.x * PLACE_CHUNK;

  for (int i = t; i < NB; i += 256) cur[i] = 0;
  __syncthreads();

  unsigned int pk[PLACE_CHUNK / 256];
  int br[PLACE_CHUNK / 256];
#pragma unroll
  for (int j = 0; j < PLACE_CHUNK / 256; ++j) {
    int i = cbase + t + j * 256;
    if (i < M) {
      int s, d;
      if (i < E) { s = ei[i]; d = ei[E + i]; } else { s = d = i - E; }
      int b = d >> BIN_SHIFT;
      int r = atomicAdd(&cur[b], 1);
      pk[j] = ((unsigned int)(d & (BIN_NODES - 1)) << 24) | (unsigned int)s;
      br[j] = (b << 16) | r;  // b<512 (15b), r<2048 (16b)
    } else {
      br[j] = -1;
    }
  }
  __syncthreads();
  for (int i = t; i < NB; i += 256) {
    int c = cur[i];
    res[i] = c ? atomicAdd(&binCursor[i], c) : 0;
  }
  __syncthreads();
#pragma unroll
  for (int j = 0; j < PLACE_CHUNK / 256; ++j) {
    if (br[j] >= 0) {
      int b = br[j] >> 16;
      int pos = res[b] + (br[j] & 0xFFFF);
      if (pos < BIN_CAP) binned[(size_t)b * BIN_CAP + pos] = pk[j];
    }
  }
}

// Per-bin rowbeg/rowend + csrc scatter (confined to the bin's own window).
__global__ __launch_bounds__(256) void csr_finalize_kernel(
    const unsigned int* __restrict__ binned, const int* __restrict__ binCursor,
    int* __restrict__ rowbeg, int* __restrict__ rowend, int* __restrict__ csrc,
    int N, int NB) {
  __shared__ int cnt[256];
  __shared__ int off[256];
  __shared__ int wsum[4];
  const int b = blockIdx.x;
  const int t = threadIdx.x;
  const int nodeBase = b << BIN_SHIFT;
  const int eBase = b * BIN_CAP;
  const int cntE = binCursor[b];

  cnt[t] = 0;
  __syncthreads();
  for (int i = t; i < cntE; i += 256) {
    atomicAdd(&cnt[binned[eBase + i] >> 24], 1);
  }
  __syncthreads();
  int v = cnt[t];
  {  // exclusive scan cnt -> off
    int lane = t & 63, wv = t >> 6;
    int x = v;
#pragma unroll
    for (int o = 1; o < 64; o <<= 1) {
      int u = __shfl_up(x, o, 64);
      if (lane >= o) x += u;
    }
    if (lane == 63) wsum[wv] = x;
    __syncthreads();
    int woff = 0;
    for (int j = 0; j < wv; j++) woff += wsum[j];
    off[t] = woff + x - v;
  }
  __syncthreads();
  int node = nodeBase + t;
  if (node < N) {
    rowbeg[node] = eBase + off[t];
    rowend[node] = eBase + off[t] + v;
  }
  cnt[t] = off[t];  // reuse as cursor
  __syncthreads();
  for (int i = t; i < cntE; i += 256) {
    unsigned int pk = binned[eBase + i];
    int r = atomicAdd(&cnt[pk >> 24], 1);
    csrc[eBase + r] = (int)(pk & 0xFFFFFFu);
  }
}

// gstart[g] = first node index with batch[node] >= g (batch sorted)
__global__ void bounds_kernel(const int* __restrict__ batch, int* __restrict__ gstart,
                              int N, int G) {
  int g = blockIdx.x * blockDim.x + threadIdx.x;
  if (g > G) return;
  int lo = 0, hi = N;
  while (lo < hi) {
    int mid = (lo + hi) >> 1;
    if (batch[mid] < g) lo = mid + 1;
    else hi = mid;
  }
  gstart[g] = lo;
}

// ---------------- dense compute ----------------

// hb[N][64] (bf16) = A[N][KDIM] @ W[KDIM][64]; fused al epilogue from the
// exact fp32 accumulators.
template <int KDIM>
__global__ __launch_bounds__(256) void gemm64(const float* __restrict__ A,
                                              const float* __restrict__ W,
                                              unsigned short* __restrict__ hb,
                                              const float* __restrict__ a_src,
                                              const float* __restrict__ a_dst,
                                              float* __restrict__ alsrc,
                                              float* __restrict__ aldst, int N) {
  __shared__ float As[32][68];
  __shared__ float Ws[32][68];
  const int block_m = blockIdx.x * 64;
  const int t = threadIdx.x;
  const int tc = t & 15;
  const int tr = t >> 4;
  const int c0 = tc * 4, r0 = tr * 4;
  float acc[4][4] = {};

  for (int kc = 0; kc < KDIM; kc += 32) {
    for (int q = t; q < 512; q += 256) {
      int node = q >> 3, f4 = q & 7;
      int gn = block_m + node;
      if (gn >= N) gn = N - 1;
      const float4 v = *(const float4*)(A + (size_t)gn * KDIM + kc + f4 * 4);
      As[f4 * 4 + 0][node] = v.x;
      As[f4 * 4 + 1][node] = v.y;
      As[f4 * 4 + 2][node] = v.z;
      As[f4 * 4 + 3][node] = v.w;
    }
    for (int q = t; q < 512; q += 256) {
      int k = q >> 4, f4 = q & 15;
      const float4 v = *(const float4*)(W + (size_t)(kc + k) * 64 + f4 * 4);
      *(float4*)&Ws[k][f4 * 4] = v;
    }
    __syncthreads();
#pragma unroll
    for (int k = 0; k < 32; ++k) {
      float4 a = *(const float4*)&As[k][r0];
      float4 b = *(const float4*)&Ws[k][c0];
      acc[0][0] += a.x * b.x; acc[0][1] += a.x * b.y; acc[0][2] += a.x * b.z; acc[0][3] += a.x * b.w;
      acc[1][0] += a.y * b.x; acc[1][1] += a.y * b.y; acc[1][2] += a.y * b.z; acc[1][3] += a.y * b.w;
      acc[2][0] += a.z * b.x; acc[2][1] += a.z * b.y; acc[2][2] += a.z * b.z; acc[2][3] += a.z * b.w;
      acc[3][0] += a.w * b.x; acc[3][1] += a.w * b.y; acc[3][2] += a.w * b.z; acc[3][3] += a.w * b.w;
    }
    __syncthreads();
  }

  const float as0 = a_src[c0], as1 = a_src[c0 + 1], as2 = a_src[c0 + 2], as3 = a_src[c0 + 3];
  const float ad0 = a_dst[c0], ad1 = a_dst[c0 + 1], ad2 = a_dst[c0 + 2], ad3 = a_dst[c0 + 3];
#pragma unroll
  for (int i = 0; i < 4; ++i) {
    int gn = block_m + r0 + i;
    if (gn < N) {
      ushort4 u;
      u.x = f2bf(acc[i][0]); u.y = f2bf(acc[i][1]);
      u.z = f2bf(acc[i][2]); u.w = f2bf(acc[i][3]);
      *(ushort4*)(hb + (size_t)gn * 64 + c0) = u;
    }
    float ps = acc[i][0] * as0 + acc[i][1] * as1 + acc[i][2] * as2 + acc[i][3] * as3;
    float pd = acc[i][0] * ad0 + acc[i][1] * ad1 + acc[i][2] * ad2 + acc[i][3] * ad3;
#pragma unroll
    for (int off = 1; off < 16; off <<= 1) {
      ps += __shfl_xor(ps, off, 64);
      pd += __shfl_xor(pd, off, 64);
    }
    if (tc == 0 && gn < N) {
      alsrc[gn] = ps;
      aldst[gn] = pd;
    }
  }
}

// Fused online-softmax + spmm (R11's proven form, 43us). One 16-lane group
// per dst node; 16-deep row burst issues before the softmax chain; valid-
// masked uniform loop; dense row write, no atomics, no LDS.
template <int ELU>
__global__ __launch_bounds__(256) void spmm_fused_kernel(
    const int* __restrict__ rowbeg, const int* __restrict__ rowend,
    const int* __restrict__ csrc,
    const float* __restrict__ alsrc, const float* __restrict__ aldst,
    const unsigned short* __restrict__ hb, const float* __restrict__ bias,
    float* __restrict__ outbuf, int N) {
  const int t = threadIdx.x;
  const int l = t & 15;   // slot within group
  const int gb = t & 48;  // group base lane within wave
  const int node = blockIdx.x * 16 + (t >> 4);
  if (node >= N) return;
  const int start = rowbeg[node];
  const int end = rowend[node];
  const float ad = aldst[node];

  float m = -1e30f;
  float ssum = 0.f;
  float4 acc0 = make_float4(0.f, 0.f, 0.f, 0.f);
  float4 acc1 = make_float4(0.f, 0.f, 0.f, 0.f);
  float4 acc2 = make_float4(0.f, 0.f, 0.f, 0.f);
  float4 acc3 = make_float4(0.f, 0.f, 0.f, 0.f);

  for (int base = start; base < end; base += 16) {
    int i = base + l;
    bool valid = i < end;
    int s = valid ? csrc[i] : 0;
    float al = alsrc[s];

    ushort4 u[16];
#pragma unroll
    for (int j = 0; j < 16; ++j) {
      int sj = __shfl(s, gb + j, 64);
      u[j] = *(const ushort4*)(hb + (size_t)sj * 64 + l * 4);
    }

    float e = al + ad;
    e = (e > 0.f) ? e : 0.2f * e;  // leaky_relu 0.2
    if (!valid) e = -1e30f;
    float cmax = e;
#pragma unroll
    for (int off = 1; off < 16; off <<= 1) cmax = fmaxf(cmax, __shfl_xor(cmax, off, 64));
    float newm = fmaxf(m, cmax);
    float scale = __expf(m - newm);
    float w = valid ? __expf(e - newm) : 0.f;
    float wsum = w;
#pragma unroll
    for (int off = 1; off < 16; off <<= 1) wsum += __shfl_xor(wsum, off, 64);
    ssum = ssum * scale + wsum;
    acc0.x *= scale; acc0.y *= scale; acc0.z *= scale; acc0.w *= scale;
    acc1.x *= scale; acc1.y *= scale; acc1.z *= scale; acc1.w *= scale;
    acc2.x *= scale; acc2.y *= scale; acc2.z *= scale; acc2.w *= scale;
    acc3.x *= scale; acc3.y *= scale; acc3.z *= scale; acc3.w *= scale;
    m = newm;

#pragma unroll
    for (int j = 0; j < 16; ++j) {
      float wj = __shfl(w, gb + j, 64);
      float4* A = ((j & 3) == 0) ? &acc0 : ((j & 3) == 1) ? &acc1
                : ((j & 3) == 2) ? &acc2 : &acc3;
      A->x += wj * bf2f(u[j].x);
      A->y += wj * bf2f(u[j].y);
      A->z += wj * bf2f(u[j].z);
      A->w += wj * bf2f(u[j].w);
    }
  }

  float inv = 1.0f / ssum;  // >= 1 edge (self-loop)
  float4 r;
  r.x = ((acc0.x + acc1.x) + (acc2.x + acc3.x)) * inv;
  r.y = ((acc0.y + acc1.y) + (acc2.y + acc3.y)) * inv;
  r.z = ((acc0.z + acc1.z) + (acc2.z + acc3.z)) * inv;
  r.w = ((acc0.w + acc1.w) + (acc2.w + acc3.w)) * inv;
  if (ELU) {
    const float4 b4 = *(const float4*)(bias + l * 4);
    r.x += b4.x; r.y += b4.y; r.z += b4.z; r.w += b4.w;
    r.x = (r.x > 0.f) ? r.x : expm1f(r.x);
    r.y = (r.y > 0.f) ? r.y : expm1f(r.y);
    r.z = (r.z > 0.f) ? r.z : expm1f(r.z);
    r.w = (r.w > 0.f) ? r.w : expm1f(r.w);
  }
  *(float4*)(outbuf + (size_t)node * 64 + l * 4) = r;
}

// bias + ELU + hierarchical mean-pool accumulation (layer 2) — R7's proven
// standalone kernel.
__global__ __launch_bounds__(256) void post_pool_kernel(
    const float* __restrict__ acc, const float* __restrict__ bias,
    const int* __restrict__ batch, float* __restrict__ pool, int N) {
  __shared__ float4 red4[16][17];
  __shared__ int sB[16];
  __shared__ int uni;
  const int t = threadIdx.x;
  const int ln = t >> 4;
  const int f4 = t & 15;
  const int base = blockIdx.x * 16;
  const int node = base + ln;

  if (t < 16) {
    int nn = base + t;
    sB[t] = (nn < N) ? batch[nn] : -1;
  }
  __syncthreads();
  if (t == 0) {
    int u = (base + 15 < N);
    for (int i = 1; i < 16; i++) u &= (sB[i] == sB[0]);
    uni = u;
  }

  float4 v = make_float4(0.f, 0.f, 0.f, 0.f);
  if (node < N) {
    v = *(const float4*)(acc + ((size_t)node * 16 + f4) * 4);
    const float4 b4 = *(const float4*)(bias + f4 * 4);
    v.x += b4.x; v.y += b4.y; v.z += b4.z; v.w += b4.w;
    v.x = (v.x > 0.f) ? v.x : expm1f(v.x);
    v.y = (v.y > 0.f) ? v.y : expm1f(v.y);
    v.z = (v.z > 0.f) ? v.z : expm1f(v.z);
    v.w = (v.w > 0.f) ? v.w : expm1f(v.w);
  }
  red4[ln][f4] = v;
  __syncthreads();

  if (t < 64) {
    const float* rf = (const float*)red4;  // row stride 68 floats
    if (uni) {
      float s = 0.f;
#pragma unroll
      for (int n = 0; n < 16; n++) s += rf[n * 68 + t];
      atomicAdd(&pool[(size_t)sB[0] * 64 + t], s);
    } else {
      for (int n = 0; n < 16; n++) {
        int g = sB[n];
        if (g >= 0) atomicAdd(&pool[(size_t)g * 64 + t], rf[n * 68 + t]);
      }
    }
  }
}

// out[g] = (pool[g,:]/cnt[g]) . Wfc + bfc ; cnt from sorted-batch bounds.
__global__ void final_kernel(const float* __restrict__ pool, const int* __restrict__ gstart,
                             const float* __restrict__ Wfc, const float* __restrict__ bfc,
                             float* __restrict__ out, int G) {
  int wid = (blockIdx.x * blockDim.x + threadIdx.x) >> 6;
  int lane = threadIdx.x & 63;
  if (wid >= G) return;
  float c = (float)max(gstart[wid + 1] - gstart[wid], 1);
  float v = pool[(size_t)wid * 64 + lane] * (1.0f / c) * Wfc[lane];
  v = wave_reduce_sum(v);
  if (lane == 0) out[wid] = v + bfc[0];
}

// ---------------------------------------------------------------------------

extern "C" void kernel_launch(void* const* d_in, const int* in_sizes, int n_in,
                              void* d_out, int out_size, void* d_ws, size_t ws_size,
                              hipStream_t stream) {
  const float* x     = (const float*)d_in[0];
  const int*   ei    = (const int*)d_in[1];
  const int*   batch = (const int*)d_in[2];
  const float* W1    = (const float*)d_in[3];
  const float* asrc1 = (const float*)d_in[4];
  const float* adst1 = (const float*)d_in[5];
  const float* b1    = (const float*)d_in[6];
  const float* W2    = (const float*)d_in[7];
  const float* asrc2 = (const float*)d_in[8];
  const float* adst2 = (const float*)d_in[9];
  const float* b2    = (const float*)d_in[10];
  const float* Wfc   = (const float*)d_in[11];
  const float* bfc   = (const float*)d_in[12];
  float* out = (float*)d_out;

  const int N = in_sizes[0] / 128;  // 100000
  const int E = in_sizes[1] / 2;    // 1600000
  const int G = 256;
  const int M = E + N;              // edges incl self-loops
  const int NB = (N + BIN_NODES - 1) >> BIN_SHIFT;  // 391 bins

  // workspace carve (256B aligned)
  char* p = (char*)d_ws;
  auto alloc = [&](size_t bytes) {
    char* r = p;
    p += (bytes + 255) & ~size_t(255);
    return r;
  };
  float*          h1e    = (float*)alloc((size_t)N * 64 * 4);
  float*          accbuf = (float*)alloc((size_t)N * 64 * 4);
  unsigned short* hb     = (unsigned short*)alloc((size_t)N * 64 * 2);
  float* alsrc  = (float*)alloc((size_t)N * 4);
  float* aldst  = (float*)alloc((size_t)N * 4);
  int*   rowbeg = (int*)alloc((size_t)N * 4);
  int*   rowend = (int*)alloc((size_t)N * 4);
  int*   csrc   = (int*)alloc((size_t)NB * BIN_CAP * 4);
  unsigned int* binned = (unsigned int*)alloc((size_t)NB * BIN_CAP * 4);
  int*   binCursor = (int*)alloc((size_t)NB * 4);
  float* pool   = (float*)alloc((size_t)G * 64 * 4);
  int*   gstart = (int*)alloc((size_t)(G + 1) * 4);

  // ---- CSR build (capacity-binned) + graph bounds ----
  hipMemsetAsync(binCursor, 0, (size_t)NB * 4, stream);
  bin_place_kernel<<<(M + PLACE_CHUNK - 1) / PLACE_CHUNK, 256, 0, stream>>>(
      ei, E, M, NB, binCursor, binned);
  csr_finalize_kernel<<<NB, 256, 0, stream>>>(binned, binCursor, rowbeg, rowend,
                                              csrc, N, NB);
  bounds_kernel<<<2, 256, 0, stream>>>(batch, gstart, N, G);

  // ---- layer 1 ----
  gemm64<128><<<(N + 63) / 64, 256, 0, stream>>>(x, W1, hb, asrc1, adst1, alsrc, aldst, N);
  spmm_fused_kernel<1><<<(N + 15) / 16, 256, 0, stream>>>(rowbeg, rowend, csrc, alsrc,
                                                          aldst, hb, b1, h1e, N);

  // ---- layer 2 ----
  gemm64<64><<<(N + 63) / 64, 256, 0, stream>>>(h1e, W2, hb, asrc2, adst2, alsrc, aldst, N);
  spmm_fused_kernel<0><<<(N + 15) / 16, 256, 0, stream>>>(rowbeg, rowend, csrc, alsrc,
                                                          aldst, hb, nullptr, accbuf, N);
  hipMemsetAsync(pool, 0, (size_t)G * 64 * 4, stream);
  post_pool_kernel<<<(N + 15) / 16, 256, 0, stream>>>(accbuf, b2, batch, pool, N);

  // ---- readout ----
  final_kernel<<<(G * 64 + 255) / 256, 256, 0, stream>>>(pool, gstart, Wfc, bfc, out, G);
}